// Round 1
// baseline (304.527 us; speedup 1.0000x reference)
//
#include <hip/hip_runtime.h>
#include <hip/hip_bf16.h>

// SOLD2 line matching on MI355X.
// Inputs: line_seg1 (1200,2,2) f32, line_seg2 (1200,2,2) f32,
//         desc1 (1,128,128,128) f32, desc2 (1,128,128,128) f32
// Outputs (concat float32): matches (1200,), nw (1200,20)

#define NLINES 1200
#define NS 5
#define DD 128
#define HH 128
#define WW 128
#define HW (HH*WW)
#define IMGM1 511.0f
#define GAPC 0.1f
#define LT 32              // lines per tile side in score kernel
#define PTS (LT*NS)        // 160 points per tile side
#define KC 32              // k-chunk
#define NPAD 1216          // 38*32
#define PPAD (NPAD*NS)     // 6080 padded points

// ---------------- K0: transpose desc [D][H][W] -> [H*W][D] ----------------
__global__ void transpose_desc(const float* __restrict__ in, float* __restrict__ out) {
    __shared__ float t[32][33];
    int s0 = blockIdx.x * 32;          // HW dim
    int d0 = blockIdx.y * 32;          // D dim
    int c = threadIdx.x;               // 0..31
    int r0 = threadIdx.y;              // 0..7
    #pragma unroll
    for (int rr = 0; rr < 32; rr += 8) {
        int d = d0 + r0 + rr;
        t[r0 + rr][c] = in[d * HW + s0 + c];
    }
    __syncthreads();
    #pragma unroll
    for (int rr = 0; rr < 32; rr += 8) {
        int s = s0 + r0 + rr;
        out[s * DD + d0 + c] = t[c][r0 + rr];
    }
}

// ---------------- K1: sample line points + bilinear descriptors -----------
__global__ void sample_kernel(const float* __restrict__ lseg,
                              const float* __restrict__ tdesc,  // [HW][D] (if use_t)
                              const float* __restrict__ desc,   // [D][H][W]
                              float* __restrict__ Dout,         // [PPAD][128]
                              float* __restrict__ valout,       // [PPAD]
                              int use_t) {
    int wave = (blockIdx.x * blockDim.x + threadIdx.x) >> 6;
    int lane = threadIdx.x & 63;
    int pt = wave;                      // 0..PPAD-1
    if (pt >= PPAD) return;
    int line = pt / NS;
    int k = pt - line * NS;

    float sy = 0.f, sx = 0.f, ey = 0.f, ex = 0.f;
    if (line < NLINES) {
        sy = lseg[line * 4 + 0]; sx = lseg[line * 4 + 1];
        ey = lseg[line * 4 + 2]; ex = lseg[line * 4 + 3];
    }
    float dy = ey - sy, dx = ex - sx;
    float len = sqrtf(dy * dy + dx * dx);
    float ns = floorf(len * 0.125f);
    ns = fminf(fmaxf(ns, 2.0f), 5.0f);
    float kf = (float)k;
    float validf = (kf < ns) ? 1.0f : 0.0f;
    float py = sy + kf * (dy / (ns - 1.0f));
    float px = sx + kf * (dx / (ns - 1.0f));
    if (validf == 0.0f) { py = 0.0f; px = 0.0f; }

    // bilinear grid mapping (exactly as reference)
    float xn = 2.0f * px / IMGM1 - 1.0f;
    float yn = 2.0f * py / IMGM1 - 1.0f;
    float ix = ((xn + 1.0f) * (float)WW - 1.0f) * 0.5f;
    float iy = ((yn + 1.0f) * (float)HH - 1.0f) * 0.5f;
    float x0f = floorf(ix), y0f = floorf(iy);
    float wx = ix - x0f, wy = iy - y0f;
    int x0 = (int)x0f, y0 = (int)y0f;

    float w00 = (1.0f - wx) * (1.0f - wy);
    float w10 = wx * (1.0f - wy);
    float w01 = (1.0f - wx) * wy;
    float w11 = wx * wy;

    float v0 = 0.0f, v1 = 0.0f;
    int xs[4] = { x0, x0 + 1, x0,     x0 + 1 };
    int ys[4] = { y0, y0,     y0 + 1, y0 + 1 };
    float ws4[4] = { w00, w10, w01, w11 };
    #pragma unroll
    for (int c = 0; c < 4; ++c) {
        int xi = xs[c], yi = ys[c];
        float inb = (xi >= 0 && xi < WW && yi >= 0 && yi < HH) ? 1.0f : 0.0f;
        int xc = min(max(xi, 0), WW - 1);
        int yc = min(max(yi, 0), HH - 1);
        if (use_t) {
            int base = (yc * WW + xc) * DD;
            v0 += tdesc[base + lane] * inb * ws4[c];
            v1 += tdesc[base + 64 + lane] * inb * ws4[c];
        } else {
            int base = yc * WW + xc;
            v0 += desc[lane * HW + base] * inb * ws4[c];
            v1 += desc[(lane + 64) * HW + base] * inb * ws4[c];
        }
    }
    float ss = v0 * v0 + v1 * v1;
    #pragma unroll
    for (int o = 32; o > 0; o >>= 1) ss += __shfl_xor(ss, o);
    float nrm = sqrtf(ss);
    Dout[pt * DD + lane] = v0 / nrm;
    Dout[pt * DD + 64 + lane] = v1 / nrm;
    if (lane == 0) valout[pt] = (line < NLINES) ? validf : 0.0f;
}

// ---------------- K2: fused score GEMM + per-line-pair reduction ----------
__launch_bounds__(256)
__global__ void score_kernel(const float* __restrict__ D1, const float* __restrict__ D2,
                             const float* __restrict__ val1, const float* __restrict__ val2,
                             float* __restrict__ lsc) {
    __shared__ float As[KC][PTS];   // k-major
    __shared__ float Bs[KC][PTS];
    int t = threadIdx.x;
    int tx = t & 15;       // i-line sub-tile
    int ty = t >> 4;       // j-line sub-tile
    int i0 = blockIdx.x * LT;
    int j0 = blockIdx.y * LT;

    float acc[2][2][5][5];
    #pragma unroll
    for (int ii = 0; ii < 2; ++ii)
        #pragma unroll
        for (int jj = 0; jj < 2; ++jj)
            #pragma unroll
            for (int a = 0; a < 5; ++a)
                #pragma unroll
                for (int b = 0; b < 5; ++b) acc[ii][jj][a][b] = 0.0f;

    int rS = t & 31;       // staging row within group of 32
    int cS = t >> 5;       // staging float4 column 0..7

    for (int kc = 0; kc < DD; kc += KC) {
        __syncthreads();
        #pragma unroll
        for (int pass = 0; pass < 5; ++pass) {
            int r = pass * 32 + rS;
            float4 va = *(const float4*)&D1[(i0 * NS + r) * DD + kc + 4 * cS];
            As[4 * cS + 0][r] = va.x; As[4 * cS + 1][r] = va.y;
            As[4 * cS + 2][r] = va.z; As[4 * cS + 3][r] = va.w;
            float4 vb = *(const float4*)&D2[(j0 * NS + r) * DD + kc + 4 * cS];
            Bs[4 * cS + 0][r] = vb.x; Bs[4 * cS + 1][r] = vb.y;
            Bs[4 * cS + 2][r] = vb.z; Bs[4 * cS + 3][r] = vb.w;
        }
        __syncthreads();
        #pragma unroll 8
        for (int k = 0; k < KC; ++k) {
            float a_[10], b_[10];
            #pragma unroll
            for (int u = 0; u < 5; ++u) {
                float2 ta = *(const float2*)&As[k][10 * tx + 2 * u];
                a_[2 * u] = ta.x; a_[2 * u + 1] = ta.y;
                float2 tb = *(const float2*)&Bs[k][10 * ty + 2 * u];
                b_[2 * u] = tb.x; b_[2 * u + 1] = tb.y;
            }
            #pragma unroll
            for (int ii = 0; ii < 2; ++ii)
                #pragma unroll
                for (int a = 0; a < 5; ++a)
                    #pragma unroll
                    for (int jj = 0; jj < 2; ++jj)
                        #pragma unroll
                        for (int b = 0; b < 5; ++b)
                            acc[ii][jj][a][b] += a_[ii * 5 + a] * b_[jj * 5 + b];
        }
    }

    // epilogue: masked 5x5 reduction per line pair
    #pragma unroll
    for (int ii = 0; ii < 2; ++ii) {
        int i = i0 + 2 * tx + ii;
        #pragma unroll
        for (int jj = 0; jj < 2; ++jj) {
            int j = j0 + 2 * ty + jj;
            if (i >= NLINES || j >= NLINES) continue;
            float S[5][5];
            #pragma unroll
            for (int a = 0; a < 5; ++a) {
                float va = val1[i * NS + a];
                #pragma unroll
                for (int b = 0; b < 5; ++b) {
                    float vb = val2[j * NS + b];
                    S[a][b] = (va != 0.0f && vb != 0.0f) ? acc[ii][jj][a][b] : -1.0f;
                }
            }
            float sum1 = 0.0f, cnt1 = 0.0f;
            #pragma unroll
            for (int a = 0; a < 5; ++a) {
                float r = S[a][0];
                #pragma unroll
                for (int b = 1; b < 5; ++b) r = fmaxf(r, S[a][b]);
                float v = (r != -1.0f) ? 1.0f : 0.0f;
                sum1 += r * v; cnt1 += v;
            }
            float sum2 = 0.0f, cnt2 = 0.0f;
            #pragma unroll
            for (int b = 0; b < 5; ++b) {
                float r = S[0][b];
                #pragma unroll
                for (int a = 1; a < 5; ++a) r = fmaxf(r, S[a][b]);
                float v = (r != -1.0f) ? 1.0f : 0.0f;
                sum2 += r * v; cnt2 += v;
            }
            lsc[i * NLINES + j] = (sum1 / cnt1 + sum2 / cnt2) * 0.5f;
        }
    }
}

// ---------------- K3a: per-row top-10 (stable-argsort semantics) ----------
__global__ void topk_kernel(const float* __restrict__ ls, int* __restrict__ topk, int dir) {
    __shared__ float sv[NLINES];
    __shared__ float rv[256];
    __shared__ int ri[256];
    int row = blockIdx.x;
    int t = threadIdx.x;
    for (int j = t; j < NLINES; j += 256)
        sv[j] = dir ? ls[j * NLINES + row] : ls[row * NLINES + j];
    __syncthreads();
    for (int sel = 0; sel < 10; ++sel) {
        float bv = -1e30f; int bi = -1;
        for (int j = t; j < NLINES; j += 256) {
            float v = sv[j];
            if (v > bv || (v == bv && j > bi)) { bv = v; bi = j; }
        }
        rv[t] = bv; ri[t] = bi;
        __syncthreads();
        for (int s = 128; s > 0; s >>= 1) {
            if (t < s) {
                float ov = rv[t + s]; int oi = ri[t + s];
                if (ov > rv[t] || (ov == rv[t] && oi > ri[t])) { rv[t] = ov; ri[t] = oi; }
            }
            __syncthreads();
        }
        if (t == 0) { topk[row * 10 + 9 - sel] = ri[0]; sv[ri[0]] = -1e30f; }
        __syncthreads();
    }
}

// ---------------- K3b: Needleman-Wunsch on top-10 (both directions) -------
__device__ __forceinline__ float nw5(const float* M) {
    float F[6] = {0, 0, 0, 0, 0, 0};
    #pragma unroll
    for (int x = 0; x < 5; ++x) {
        float diag = F[0];
        float left = 0.0f;
        #pragma unroll
        for (int y = 1; y <= 5; ++y) {
            float up = F[y];
            float cur = fmaxf(fmaxf(left, up), diag + (M[x * 5 + y - 1] - GAPC));
            F[y] = cur; left = cur; diag = up;
        }
    }
    return F[5];
}

__global__ void nw_kernel(const float* __restrict__ D1, const float* __restrict__ D2,
                          const float* __restrict__ val1, const float* __restrict__ val2,
                          const int* __restrict__ topk1, const int* __restrict__ topk2,
                          float* __restrict__ nwout, float* __restrict__ nw2buf) {
    int w = (blockIdx.x * blockDim.x + threadIdx.x) >> 6;
    int lane = threadIdx.x & 63;
    if (w >= 24000) return;
    int dir = (w >= 12000) ? 1 : 0;
    int rem = w - dir * 12000;
    int row = rem / 10, r = rem - (rem / 10) * 10;
    int i, j;
    if (!dir) { i = row; j = topk1[row * 10 + r]; }
    else      { j = row; i = topk2[row * 10 + r]; }

    float d1a[5], d1b[5], d2a[5], d2b[5];
    #pragma unroll
    for (int p = 0; p < 5; ++p) {
        d1a[p] = D1[(i * NS + p) * DD + lane];
        d1b[p] = D1[(i * NS + p) * DD + 64 + lane];
        d2a[p] = D2[(j * NS + p) * DD + lane];
        d2b[p] = D2[(j * NS + p) * DD + 64 + lane];
    }
    float part[25];
    #pragma unroll
    for (int a = 0; a < 5; ++a)
        #pragma unroll
        for (int b = 0; b < 5; ++b)
            part[a * 5 + b] = d1a[a] * d2a[b] + d1b[a] * d2b[b];
    #pragma unroll
    for (int o = 32; o > 0; o >>= 1) {
        #pragma unroll
        for (int q = 0; q < 25; ++q) part[q] += __shfl_xor(part[q], o);
    }
    if (lane == 0) {
        float S[25];
        #pragma unroll
        for (int a = 0; a < 5; ++a) {
            float va = val1[i * NS + a];
            #pragma unroll
            for (int b = 0; b < 5; ++b) {
                float vb = val2[j * NS + b];
                S[a * 5 + b] = (va != 0.0f && vb != 0.0f) ? part[a * 5 + b] : -1.0f;
            }
        }
        float M1[25], M2[25];
        if (!dir) {
            #pragma unroll
            for (int x = 0; x < 5; ++x)
                #pragma unroll
                for (int y = 0; y < 5; ++y) {
                    M1[x * 5 + y] = S[x * 5 + y];
                    M2[x * 5 + y] = S[x * 5 + (4 - y)];
                }
        } else {
            #pragma unroll
            for (int x = 0; x < 5; ++x)
                #pragma unroll
                for (int y = 0; y < 5; ++y) {
                    M1[x * 5 + y] = S[y * 5 + x];
                    M2[x * 5 + y] = S[(4 - y) * 5 + x];
                }
        }
        float n1 = nw5(M1);
        float n2 = nw5(M2);
        if (!dir) { nwout[row * 20 + r] = n1; nwout[row * 20 + 10 + r] = n2; }
        else      { nw2buf[row * 20 + r] = n1; nw2buf[row * 20 + 10 + r] = n2; }
    }
}

// ---------------- K3c: argmax over 20 + mutual check ----------------------
__global__ void argmax_kernel(const float* __restrict__ nw1, const float* __restrict__ nw2,
                              const int* __restrict__ topk1, const int* __restrict__ topk2,
                              int* __restrict__ mpre, int* __restrict__ m2) {
    int t = blockIdx.x * 256 + threadIdx.x;
    if (t >= 2400) return;
    int dir = t / NLINES, row = t - dir * NLINES;
    const float* nw = (dir ? nw2 : nw1) + row * 20;
    float best = nw[0]; int bi = 0;
    #pragma unroll
    for (int q = 1; q < 20; ++q) {
        float v = nw[q];
        if (v > best) { best = v; bi = q; }
    }
    int m = (dir ? topk2 : topk1)[row * 10 + (bi % 10)];
    if (dir) m2[row] = m; else mpre[row] = m;
}

__global__ void final_kernel(const int* __restrict__ mpre, const int* __restrict__ m2,
                             float* __restrict__ out) {
    int i = blockIdx.x * 256 + threadIdx.x;
    if (i >= NLINES) return;
    int m = mpre[i];
    out[i] = (m2[m] == i) ? (float)m : -1.0f;
}

extern "C" void kernel_launch(void* const* d_in, const int* in_sizes, int n_in,
                              void* d_out, int out_size, void* d_ws, size_t ws_size,
                              hipStream_t stream) {
    const float* lseg1 = (const float*)d_in[0];
    const float* lseg2 = (const float*)d_in[1];
    const float* desc1 = (const float*)d_in[2];
    const float* desc2 = (const float*)d_in[3];
    float* out = (float*)d_out;

    float* wsf = (float*)d_ws;
    size_t off = 0;
    float* D1 = wsf + off;     off += (size_t)PPAD * DD;
    float* D2 = wsf + off;     off += (size_t)PPAD * DD;
    float* val1 = wsf + off;   off += PPAD;
    float* val2 = wsf + off;   off += PPAD;
    float* lsc = wsf + off;    off += (size_t)NLINES * NLINES;
    int* topk1 = (int*)(wsf + off); off += NLINES * 10;
    int* topk2 = (int*)(wsf + off); off += NLINES * 10;
    int* mpre = (int*)(wsf + off);  off += 1280;
    int* m2 = (int*)(wsf + off);    off += 1280;
    float* nw2buf = wsf + off; off += NLINES * 20;
    float* tdesc1 = wsf + off; off += (size_t)HW * DD;
    float* tdesc2 = wsf + off; off += (size_t)HW * DD;
    size_t need_full = off * sizeof(float);
    int use_t = (ws_size >= need_full) ? 1 : 0;

    if (use_t) {
        transpose_desc<<<dim3(HW / 32, DD / 32), dim3(32, 8), 0, stream>>>(desc1, tdesc1);
        transpose_desc<<<dim3(HW / 32, DD / 32), dim3(32, 8), 0, stream>>>(desc2, tdesc2);
    }
    sample_kernel<<<PPAD / 4, 256, 0, stream>>>(lseg1, tdesc1, desc1, D1, val1, use_t);
    sample_kernel<<<PPAD / 4, 256, 0, stream>>>(lseg2, tdesc2, desc2, D2, val2, use_t);

    score_kernel<<<dim3(NPAD / LT, NPAD / LT), 256, 0, stream>>>(D1, D2, val1, val2, lsc);

    topk_kernel<<<NLINES, 256, 0, stream>>>(lsc, topk1, 0);
    topk_kernel<<<NLINES, 256, 0, stream>>>(lsc, topk2, 1);

    nw_kernel<<<24000 / 4, 256, 0, stream>>>(D1, D2, val1, val2, topk1, topk2,
                                             out + NLINES, nw2buf);

    argmax_kernel<<<10, 256, 0, stream>>>(out + NLINES, nw2buf, topk1, topk2, mpre, m2);
    final_kernel<<<5, 256, 0, stream>>>(mpre, m2, out);
}

// Round 2
// 240.697 us; speedup vs baseline: 1.2652x; 1.2652x over previous
//
#include <hip/hip_runtime.h>
#include <hip/hip_bf16.h>

// SOLD2 line matching on MI355X.
// Inputs: line_seg1 (1200,2,2) f32, line_seg2 (1200,2,2) f32,
//         desc1 (1,128,128,128) f32, desc2 (1,128,128,128) f32
// Outputs (concat float32): matches (1200,), nw (1200,20)

#define NLINES 1200
#define NS 5
#define DD 128
#define HH 128
#define WW 128
#define HW (HH*WW)
#define IMGM1 511.0f
#define GAPC 0.1f
#define NPAD 1216          // 38*32
#define PPAD (NPAD*NS)     // 6080 padded points
#define KEXT 384           // 3-term bf16 split: [hi,lo,hi] x [hi,hi,lo]

typedef __attribute__((ext_vector_type(8))) short short8;
typedef __attribute__((ext_vector_type(4))) float f32x4;

__device__ __forceinline__ void async_cp16(const void* g, void* l) {
    __builtin_amdgcn_global_load_lds(
        (const __attribute__((address_space(1))) void*)g,
        (__attribute__((address_space(3))) void*)l, 16, 0, 0);
}

// ---------------- K0: transpose desc [D][H][W] -> [H*W][D] ----------------
__global__ void transpose_desc(const float* __restrict__ in, float* __restrict__ out) {
    __shared__ float t[32][33];
    int s0 = blockIdx.x * 32;          // HW dim
    int d0 = blockIdx.y * 32;          // D dim
    int c = threadIdx.x;               // 0..31
    int r0 = threadIdx.y;              // 0..7
    #pragma unroll
    for (int rr = 0; rr < 32; rr += 8) {
        int d = d0 + r0 + rr;
        t[r0 + rr][c] = in[d * HW + s0 + c];
    }
    __syncthreads();
    #pragma unroll
    for (int rr = 0; rr < 32; rr += 8) {
        int s = s0 + r0 + rr;
        out[s * DD + d0 + c] = t[c][r0 + rr];
    }
}

// ---------------- K1: sample line points + bilinear descriptors -----------
__global__ void sample_kernel(const float* __restrict__ lseg,
                              const float* __restrict__ tdesc,  // [HW][D] (if use_t)
                              const float* __restrict__ desc,   // [D][H][W]
                              float* __restrict__ Dout,         // [PPAD][128]
                              float* __restrict__ valout,       // [PPAD]
                              int use_t) {
    int wave = (blockIdx.x * blockDim.x + threadIdx.x) >> 6;
    int lane = threadIdx.x & 63;
    int pt = wave;                      // 0..PPAD-1
    if (pt >= PPAD) return;
    int line = pt / NS;
    int k = pt - line * NS;

    float sy = 0.f, sx = 0.f, ey = 0.f, ex = 0.f;
    if (line < NLINES) {
        sy = lseg[line * 4 + 0]; sx = lseg[line * 4 + 1];
        ey = lseg[line * 4 + 2]; ex = lseg[line * 4 + 3];
    }
    float dy = ey - sy, dx = ex - sx;
    float len = sqrtf(dy * dy + dx * dx);
    float ns = floorf(len * 0.125f);
    ns = fminf(fmaxf(ns, 2.0f), 5.0f);
    float kf = (float)k;
    float validf = (kf < ns) ? 1.0f : 0.0f;
    float py = sy + kf * (dy / (ns - 1.0f));
    float px = sx + kf * (dx / (ns - 1.0f));
    if (validf == 0.0f) { py = 0.0f; px = 0.0f; }

    float xn = 2.0f * px / IMGM1 - 1.0f;
    float yn = 2.0f * py / IMGM1 - 1.0f;
    float ix = ((xn + 1.0f) * (float)WW - 1.0f) * 0.5f;
    float iy = ((yn + 1.0f) * (float)HH - 1.0f) * 0.5f;
    float x0f = floorf(ix), y0f = floorf(iy);
    float wx = ix - x0f, wy = iy - y0f;
    int x0 = (int)x0f, y0 = (int)y0f;

    float w00 = (1.0f - wx) * (1.0f - wy);
    float w10 = wx * (1.0f - wy);
    float w01 = (1.0f - wx) * wy;
    float w11 = wx * wy;

    float v0 = 0.0f, v1 = 0.0f;
    int xs[4] = { x0, x0 + 1, x0,     x0 + 1 };
    int ys[4] = { y0, y0,     y0 + 1, y0 + 1 };
    float ws4[4] = { w00, w10, w01, w11 };
    #pragma unroll
    for (int c = 0; c < 4; ++c) {
        int xi = xs[c], yi = ys[c];
        float inb = (xi >= 0 && xi < WW && yi >= 0 && yi < HH) ? 1.0f : 0.0f;
        int xc = min(max(xi, 0), WW - 1);
        int yc = min(max(yi, 0), HH - 1);
        if (use_t) {
            int base = (yc * WW + xc) * DD;
            v0 += tdesc[base + lane] * inb * ws4[c];
            v1 += tdesc[base + 64 + lane] * inb * ws4[c];
        } else {
            int base = yc * WW + xc;
            v0 += desc[lane * HW + base] * inb * ws4[c];
            v1 += desc[(lane + 64) * HW + base] * inb * ws4[c];
        }
    }
    float ss = v0 * v0 + v1 * v1;
    #pragma unroll
    for (int o = 32; o > 0; o >>= 1) ss += __shfl_xor(ss, o);
    if (ss == 0.0f) ss = 1.0f;   // padding lines: avoid 0/0 NaN
    float nrm = sqrtf(ss);
    Dout[pt * DD + lane] = v0 / nrm;
    Dout[pt * DD + 64 + lane] = v1 / nrm;
    if (lane == 0) valout[pt] = (line < NLINES) ? validf : 0.0f;
}

// ---------------- K1b: split fp32 -> 3-term bf16 extended operand ---------
// arole=1: [hi, lo, hi]  (A side);  arole=0: [hi, hi, lo]  (B side)
__global__ void split_kernel(const float* __restrict__ D, short* __restrict__ E, int arole) {
    int idx = blockIdx.x * 256 + threadIdx.x;   // over PPAD*DD
    if (idx >= PPAD * DD) return;
    int pt = idx >> 7, k = idx & 127;
    float x = D[idx];
    __hip_bfloat16 h = __float2bfloat16(x);
    float hf = __bfloat162float(h);
    __hip_bfloat16 l = __float2bfloat16(x - hf);
    short hs = *(short*)&h;
    short lo = *(short*)&l;
    size_t base = (size_t)pt * KEXT + k;
    if (arole) { E[base] = hs; E[base + 128] = lo; E[base + 256] = hs; }
    else       { E[base] = hs; E[base + 128] = hs; E[base + 256] = lo; }
}

// ---------------- K2: MFMA score GEMM + fused per-line-pair reduction -----
// Block: 160x160 points (32x32 lines), 4 waves in 2x2, each wave 80x80
// via 5x5 tiles of mfma_f32_16x16x32_bf16 over K=384.
__launch_bounds__(256, 2)
__global__ void score_kernel(const short* __restrict__ Aext, const short* __restrict__ Bext,
                             const float* __restrict__ val1, const float* __restrict__ val2,
                             float* __restrict__ lsc) {
    __shared__ union {
        struct { short A[160 * 64]; short B[160 * 64]; } st;   // 40960 B
        float dump[80 * 161];                                   // 51520 B
    } u;

    const int t = threadIdx.x;
    const int lane = t & 63;
    const int w = t >> 6;           // wave 0..3
    const int wm = w >> 1;          // 0..1 row half
    const int wn = w & 1;           // 0..1 col half
    const int i0pt = blockIdx.x * 160;
    const int j0pt = blockIdx.y * 160;

    // staging lane decomposition: 64 lanes = 8 rows x 8 chunks(16B)
    const int rl = lane >> 3;                       // row in 8-group
    const int cg = (lane & 7) ^ rl;                 // swizzled global chunk
    const int rbase = 40 * w;                       // this wave's staging rows

    f32x4 acc[5][5];
    #pragma unroll
    for (int a = 0; a < 5; ++a)
        #pragma unroll
        for (int b = 0; b < 5; ++b)
            acc[a][b] = (f32x4){0.f, 0.f, 0.f, 0.f};

    for (int kc = 0; kc < KEXT; kc += 64) {
        __syncthreads();
        #pragma unroll
        for (int p = 0; p < 5; ++p) {
            int row = rbase + 8 * p + rl;
            const short* ga = Aext + (size_t)(i0pt + row) * KEXT + kc + cg * 8;
            async_cp16(ga, &u.st.A[(rbase + 8 * p) * 64]);
            const short* gb = Bext + (size_t)(j0pt + row) * KEXT + kc + cg * 8;
            async_cp16(gb, &u.st.B[(rbase + 8 * p) * 64]);
        }
        __syncthreads();
        #pragma unroll
        for (int ks = 0; ks < 2; ++ks) {
            int s = (ks * 4 + (lane >> 4)) ^ (lane & 7);   // swizzled slot
            short8 af[5], bf_[5];
            #pragma unroll
            for (int ti = 0; ti < 5; ++ti) {
                int rowA = 80 * wm + 16 * ti + (lane & 15);
                af[ti] = *(const short8*)&u.st.A[rowA * 64 + s * 8];
            }
            #pragma unroll
            for (int tj = 0; tj < 5; ++tj) {
                int rowB = 80 * wn + 16 * tj + (lane & 15);
                bf_[tj] = *(const short8*)&u.st.B[rowB * 64 + s * 8];
            }
            #pragma unroll
            for (int ti = 0; ti < 5; ++ti)
                #pragma unroll
                for (int tj = 0; tj < 5; ++tj)
                    acc[ti][tj] = __builtin_amdgcn_mfma_f32_16x16x32_bf16(
                        af[ti], bf_[tj], acc[ti][tj], 0, 0, 0);
        }
    }

    // fused epilogue: two phases of 80 rows through LDS, then 5x5 reduction
    const int i0l = blockIdx.x * 32;
    const int j0l = blockIdx.y * 32;
    #pragma unroll
    for (int p = 0; p < 2; ++p) {
        __syncthreads();
        if (wm == p) {
            #pragma unroll
            for (int ti = 0; ti < 5; ++ti) {
                #pragma unroll
                for (int reg = 0; reg < 4; ++reg) {
                    int rloc = 16 * ti + (lane >> 4) * 4 + reg;
                    #pragma unroll
                    for (int tj = 0; tj < 5; ++tj) {
                        int col = 80 * wn + 16 * tj + (lane & 15);
                        u.dump[rloc * 161 + col] = acc[ti][tj][reg];
                    }
                }
            }
        }
        __syncthreads();
        #pragma unroll
        for (int e = 0; e < 2; ++e) {
            int q = t * 2 + e;            // 0..511 line pairs
            int li = q >> 5, lj = q & 31;
            int i = i0l + 16 * p + li;
            int j = j0l + lj;
            if (i < NLINES && j < NLINES) {
                float S[5][5];
                #pragma unroll
                for (int a = 0; a < 5; ++a) {
                    float va = val1[i * NS + a];
                    #pragma unroll
                    for (int b = 0; b < 5; ++b) {
                        float vb = val2[j * NS + b];
                        float sc = u.dump[(li * 5 + a) * 161 + (lj * 5 + b)];
                        S[a][b] = (va != 0.0f && vb != 0.0f) ? sc : -1.0f;
                    }
                }
                float sum1 = 0.0f, cnt1 = 0.0f;
                #pragma unroll
                for (int a = 0; a < 5; ++a) {
                    float r = S[a][0];
                    #pragma unroll
                    for (int b = 1; b < 5; ++b) r = fmaxf(r, S[a][b]);
                    float v = (r != -1.0f) ? 1.0f : 0.0f;
                    sum1 += r * v; cnt1 += v;
                }
                float sum2 = 0.0f, cnt2 = 0.0f;
                #pragma unroll
                for (int b = 0; b < 5; ++b) {
                    float r = S[0][b];
                    #pragma unroll
                    for (int a = 1; a < 5; ++a) r = fmaxf(r, S[a][b]);
                    float v = (r != -1.0f) ? 1.0f : 0.0f;
                    sum2 += r * v; cnt2 += v;
                }
                lsc[i * NLINES + j] = (sum1 / cnt1 + sum2 / cnt2) * 0.5f;
            }
        }
    }
}

// ---------------- K3a: per-row top-10 (stable-argsort semantics) ----------
__global__ void topk_kernel(const float* __restrict__ ls, int* __restrict__ topk, int dir) {
    __shared__ float sv[NLINES];
    __shared__ float wv[4];
    __shared__ int wi[4];
    int row = blockIdx.x;
    int t = threadIdx.x;
    int lane = t & 63, w = t >> 6;
    for (int j = t; j < NLINES; j += 256)
        sv[j] = dir ? ls[j * NLINES + row] : ls[row * NLINES + j];
    __syncthreads();
    for (int sel = 0; sel < 10; ++sel) {
        float bv = -1e30f; int bi = -1;
        for (int j = t; j < NLINES; j += 256) {
            float v = sv[j];
            if (v > bv || (v == bv && j > bi)) { bv = v; bi = j; }
        }
        #pragma unroll
        for (int o = 32; o > 0; o >>= 1) {
            float ov = __shfl_xor(bv, o);
            int oi = __shfl_xor(bi, o);
            if (ov > bv || (ov == bv && oi > bi)) { bv = ov; bi = oi; }
        }
        if (lane == 0) { wv[w] = bv; wi[w] = bi; }
        __syncthreads();
        if (t == 0) {
            float fv = wv[0]; int fi = wi[0];
            #pragma unroll
            for (int qq = 1; qq < 4; ++qq)
                if (wv[qq] > fv || (wv[qq] == fv && wi[qq] > fi)) { fv = wv[qq]; fi = wi[qq]; }
            topk[row * 10 + 9 - sel] = fi;
            sv[fi] = -1e30f;
        }
        __syncthreads();
    }
}

// ---------------- K3b: Needleman-Wunsch on top-10 (both directions) -------
__device__ __forceinline__ float nw5(const float* M) {
    float F[6] = {0, 0, 0, 0, 0, 0};
    #pragma unroll
    for (int x = 0; x < 5; ++x) {
        float diag = F[0];
        float left = 0.0f;
        #pragma unroll
        for (int y = 1; y <= 5; ++y) {
            float up = F[y];
            float cur = fmaxf(fmaxf(left, up), diag + (M[x * 5 + y - 1] - GAPC));
            F[y] = cur; left = cur; diag = up;
        }
    }
    return F[5];
}

__global__ void nw_kernel(const float* __restrict__ D1, const float* __restrict__ D2,
                          const float* __restrict__ val1, const float* __restrict__ val2,
                          const int* __restrict__ topk1, const int* __restrict__ topk2,
                          float* __restrict__ nwout, float* __restrict__ nw2buf) {
    int w = (blockIdx.x * blockDim.x + threadIdx.x) >> 6;
    int lane = threadIdx.x & 63;
    if (w >= 24000) return;
    int dir = (w >= 12000) ? 1 : 0;
    int rem = w - dir * 12000;
    int row = rem / 10, r = rem - (rem / 10) * 10;
    int i, j;
    if (!dir) { i = row; j = topk1[row * 10 + r]; }
    else      { j = row; i = topk2[row * 10 + r]; }

    float d1a[5], d1b[5], d2a[5], d2b[5];
    #pragma unroll
    for (int p = 0; p < 5; ++p) {
        d1a[p] = D1[(i * NS + p) * DD + lane];
        d1b[p] = D1[(i * NS + p) * DD + 64 + lane];
        d2a[p] = D2[(j * NS + p) * DD + lane];
        d2b[p] = D2[(j * NS + p) * DD + 64 + lane];
    }
    float part[25];
    #pragma unroll
    for (int a = 0; a < 5; ++a)
        #pragma unroll
        for (int b = 0; b < 5; ++b)
            part[a * 5 + b] = d1a[a] * d2a[b] + d1b[a] * d2b[b];
    #pragma unroll
    for (int o = 32; o > 0; o >>= 1) {
        #pragma unroll
        for (int q = 0; q < 25; ++q) part[q] += __shfl_xor(part[q], o);
    }
    if (lane == 0) {
        float S[25];
        #pragma unroll
        for (int a = 0; a < 5; ++a) {
            float va = val1[i * NS + a];
            #pragma unroll
            for (int b = 0; b < 5; ++b) {
                float vb = val2[j * NS + b];
                S[a * 5 + b] = (va != 0.0f && vb != 0.0f) ? part[a * 5 + b] : -1.0f;
            }
        }
        float M1[25], M2[25];
        if (!dir) {
            #pragma unroll
            for (int x = 0; x < 5; ++x)
                #pragma unroll
                for (int y = 0; y < 5; ++y) {
                    M1[x * 5 + y] = S[x * 5 + y];
                    M2[x * 5 + y] = S[x * 5 + (4 - y)];
                }
        } else {
            #pragma unroll
            for (int x = 0; x < 5; ++x)
                #pragma unroll
                for (int y = 0; y < 5; ++y) {
                    M1[x * 5 + y] = S[y * 5 + x];
                    M2[x * 5 + y] = S[(4 - y) * 5 + x];
                }
        }
        float n1 = nw5(M1);
        float n2 = nw5(M2);
        if (!dir) { nwout[row * 20 + r] = n1; nwout[row * 20 + 10 + r] = n2; }
        else      { nw2buf[row * 20 + r] = n1; nw2buf[row * 20 + 10 + r] = n2; }
    }
}

// ---------------- K3c: argmax over 20 + mutual check ----------------------
__global__ void argmax_kernel(const float* __restrict__ nw1, const float* __restrict__ nw2,
                              const int* __restrict__ topk1, const int* __restrict__ topk2,
                              int* __restrict__ mpre, int* __restrict__ m2) {
    int t = blockIdx.x * 256 + threadIdx.x;
    if (t >= 2400) return;
    int dir = t / NLINES, row = t - dir * NLINES;
    const float* nw = (dir ? nw2 : nw1) + row * 20;
    float best = nw[0]; int bi = 0;
    #pragma unroll
    for (int q = 1; q < 20; ++q) {
        float v = nw[q];
        if (v > best) { best = v; bi = q; }
    }
    int m = (dir ? topk2 : topk1)[row * 10 + (bi % 10)];
    if (dir) m2[row] = m; else mpre[row] = m;
}

__global__ void final_kernel(const int* __restrict__ mpre, const int* __restrict__ m2,
                             float* __restrict__ out) {
    int i = blockIdx.x * 256 + threadIdx.x;
    if (i >= NLINES) return;
    int m = mpre[i];
    out[i] = (m2[m] == i) ? (float)m : -1.0f;
}

extern "C" void kernel_launch(void* const* d_in, const int* in_sizes, int n_in,
                              void* d_out, int out_size, void* d_ws, size_t ws_size,
                              hipStream_t stream) {
    const float* lseg1 = (const float*)d_in[0];
    const float* lseg2 = (const float*)d_in[1];
    const float* desc1 = (const float*)d_in[2];
    const float* desc2 = (const float*)d_in[3];
    float* out = (float*)d_out;

    float* wsf = (float*)d_ws;
    size_t off = 0;
    float* D1 = wsf + off;     off += (size_t)PPAD * DD;
    float* D2 = wsf + off;     off += (size_t)PPAD * DD;
    float* val1 = wsf + off;   off += PPAD;
    float* val2 = wsf + off;   off += PPAD;
    float* lsc = wsf + off;    off += (size_t)NLINES * NLINES;
    int* topk1 = (int*)(wsf + off); off += NLINES * 10;
    int* topk2 = (int*)(wsf + off); off += NLINES * 10;
    int* mpre = (int*)(wsf + off);  off += 1280;
    int* m2 = (int*)(wsf + off);    off += 1280;
    float* nw2buf = wsf + off; off += NLINES * 20;
    short* Aext = (short*)(wsf + off); off += (size_t)PPAD * KEXT / 2;
    short* Bext = (short*)(wsf + off); off += (size_t)PPAD * KEXT / 2;
    float* tdesc1 = wsf + off; off += (size_t)HW * DD;
    float* tdesc2 = wsf + off; off += (size_t)HW * DD;
    size_t need_full = off * sizeof(float);
    int use_t = (ws_size >= need_full) ? 1 : 0;

    if (use_t) {
        transpose_desc<<<dim3(HW / 32, DD / 32), dim3(32, 8), 0, stream>>>(desc1, tdesc1);
        transpose_desc<<<dim3(HW / 32, DD / 32), dim3(32, 8), 0, stream>>>(desc2, tdesc2);
    }
    sample_kernel<<<PPAD / 4, 256, 0, stream>>>(lseg1, tdesc1, desc1, D1, val1, use_t);
    sample_kernel<<<PPAD / 4, 256, 0, stream>>>(lseg2, tdesc2, desc2, D2, val2, use_t);

    split_kernel<<<(PPAD * DD) / 256, 256, 0, stream>>>(D1, Aext, 1);
    split_kernel<<<(PPAD * DD) / 256, 256, 0, stream>>>(D2, Bext, 0);

    score_kernel<<<dim3(NPAD / 32, NPAD / 32), 256, 0, stream>>>(Aext, Bext, val1, val2, lsc);

    topk_kernel<<<NLINES, 256, 0, stream>>>(lsc, topk1, 0);
    topk_kernel<<<NLINES, 256, 0, stream>>>(lsc, topk2, 1);

    nw_kernel<<<24000 / 4, 256, 0, stream>>>(D1, D2, val1, val2, topk1, topk2,
                                             out + NLINES, nw2buf);

    argmax_kernel<<<10, 256, 0, stream>>>(out + NLINES, nw2buf, topk1, topk2, mpre, m2);
    final_kernel<<<5, 256, 0, stream>>>(mpre, m2, out);
}